// Round 6
// baseline (534.382 us; speedup 1.0000x reference)
//
#include <hip/hip_runtime.h>
#include <hip/hip_bf16.h>

// ---------------------------------------------------------------------------
// Swin cross-attention block, MI355X (gfx950).
// Config: B=16, H=W=56, C=512, WS=7, SHIFT=3, NH=16, HD=32, N=49, NW=64.
// M = B*NW*N = 50176 rows. Only q_b, k_a, v_a are consumed by the reference.
//
// Workspace (~260 MB):
//   xw : 50176x512 bf16  [reused as attn_out]
//   yw : 50176x512 bf16
//   qb/kb/vb : 50176x512 bf16 (row=win*49+n, col=head*32+d)
//   Wt : 2048x512 bf16 (transposed weight panels)
//   biasT : [4 masks][16 heads][col 64][row 64] fp32 (TRANSPOSED: col-major)
// ---------------------------------------------------------------------------

typedef short bf16x8 __attribute__((ext_vector_type(8)));
typedef float f32x4 __attribute__((ext_vector_type(4)));
typedef unsigned short u16;

#define MTOT 50176
#define SCALE_ 0.17677669529663687f

__device__ __forceinline__ u16 f2bf(float f) {
    __hip_bfloat16 h = __float2bfloat16(f);
    return *reinterpret_cast<u16*>(&h);
}
__device__ __forceinline__ float bf2f(u16 u) {
    union { unsigned int i; float f; } t; t.i = ((unsigned int)u) << 16; return t.f;
}

#define ASYNC_COPY16(g, l)                                                      \
    __builtin_amdgcn_global_load_lds((__attribute__((address_space(1))) void*)(g), \
                                     (__attribute__((address_space(3))) void*)(l), 16, 0, 0)

// ---------------------------------------------------------------------------
// Kernel 1: weight transpose + fp32->bf16.  Wt[r][k], r = output col.
// ---------------------------------------------------------------------------
__global__ __launch_bounds__(256) void wconv_kernel(
    const float* __restrict__ Wqkv_a, const float* __restrict__ Wqkv_b,
    const float* __restrict__ Wproj, u16* __restrict__ Wt)
{
    const int idx = blockIdx.x * 256 + threadIdx.x;   // 2048*512
    const int r = idx >> 9;
    const int k = idx & 511;
    float val;
    if (r < 512)       val = Wqkv_b[k * 1536 + r];
    else if (r < 1536) val = Wqkv_a[k * 1536 + r];
    else               val = Wproj[k * 512 + (r - 1536)];
    Wt[idx] = f2bf(val);
}

// ---------------------------------------------------------------------------
// Kernel 1b: per-(mask,head) bias table, TRANSPOSED: biasT[blk][col*64+row].
// rpb + shifted-window mask; padded rows/cols (>=49) = -3e38.
// ---------------------------------------------------------------------------
__global__ __launch_bounds__(256) void build_bias_kernel(
    const float* __restrict__ rpb, float* __restrict__ biasT)
{
    const int blk = blockIdx.x;           // 64 = mid*16 + head
    const int mid = blk >> 4, head = blk & 15;
    const int whq = (mid >> 1) & 1, wwq = mid & 1;
    for (int t = threadIdx.x; t < 4096; t += 256) {
        const int col = t >> 6, row = t & 63;     // t = col*64 + row
        float v;
        if (row < 49 && col < 49) {
            const int ih = row / 7, iw = row - ih * 7;
            const int jh = col / 7, jw = col - jh * 7;
            v = rpb[((ih - jh + 6) * 13 + (iw - jw + 6)) * 16 + head];
            const int li = (whq ? (ih < 4 ? 1 : 2) : 0) * 3 + (wwq ? (iw < 4 ? 1 : 2) : 0);
            const int lj = (whq ? (jh < 4 ? 1 : 2) : 0) * 3 + (wwq ? (jw < 4 ? 1 : 2) : 0);
            if (li != lj) v -= 100.0f;
        } else {
            v = -3.0e38f;
        }
        biasT[(size_t)blk * 4096 + t] = v;
    }
}

// ---------------------------------------------------------------------------
// Kernel 2: LayerNorm + roll(-3,-3) + window partition, both streams -> bf16.
// ---------------------------------------------------------------------------
__device__ __forceinline__ void ln_one(
    const float* __restrict__ src, const float* __restrict__ g,
    const float* __restrict__ bt, u16* __restrict__ dst, int lane)
{
    const float4 v0 = *(const float4*)(src + lane * 8);
    const float4 v1 = *(const float4*)(src + lane * 8 + 4);
    float s = v0.x + v0.y + v0.z + v0.w + v1.x + v1.y + v1.z + v1.w;
    float q = v0.x*v0.x + v0.y*v0.y + v0.z*v0.z + v0.w*v0.w
            + v1.x*v1.x + v1.y*v1.y + v1.z*v1.z + v1.w*v1.w;
#pragma unroll
    for (int o = 32; o >= 1; o >>= 1) { s += __shfl_xor(s, o); q += __shfl_xor(q, o); }
    const float mean = s * (1.0f / 512.0f);
    const float rstd = rsqrtf(q * (1.0f / 512.0f) - mean * mean + 1e-5f);
    const float4 g0 = *(const float4*)(g + lane * 8);
    const float4 g1 = *(const float4*)(g + lane * 8 + 4);
    const float4 b0 = *(const float4*)(bt + lane * 8);
    const float4 b1 = *(const float4*)(bt + lane * 8 + 4);
    u16 o8[8];
    o8[0] = f2bf((v0.x - mean) * rstd * g0.x + b0.x);
    o8[1] = f2bf((v0.y - mean) * rstd * g0.y + b0.y);
    o8[2] = f2bf((v0.z - mean) * rstd * g0.z + b0.z);
    o8[3] = f2bf((v0.w - mean) * rstd * g0.w + b0.w);
    o8[4] = f2bf((v1.x - mean) * rstd * g1.x + b1.x);
    o8[5] = f2bf((v1.y - mean) * rstd * g1.y + b1.y);
    o8[6] = f2bf((v1.z - mean) * rstd * g1.z + b1.z);
    o8[7] = f2bf((v1.w - mean) * rstd * g1.w + b1.w);
    int4 pk;
    pk.x = (int)(((unsigned)o8[1] << 16) | o8[0]);
    pk.y = (int)(((unsigned)o8[3] << 16) | o8[2]);
    pk.z = (int)(((unsigned)o8[5] << 16) | o8[4]);
    pk.w = (int)(((unsigned)o8[7] << 16) | o8[6]);
    *(int4*)(dst + lane * 8) = pk;
}

__global__ __launch_bounds__(256) void ln_window_kernel(
    const float* __restrict__ xa, const float* __restrict__ xb,
    const float* __restrict__ ga, const float* __restrict__ bea,
    const float* __restrict__ gb, const float* __restrict__ beb,
    u16* __restrict__ xw, u16* __restrict__ yw)
{
    const int wave = threadIdx.x >> 6, lane = threadIdx.x & 63;
    const int row = blockIdx.x * 4 + wave;             // < 50176
    const int win = row / 49, n = row - win * 49;
    const int b = win >> 6, wi = win & 63;
    const int wh = wi >> 3, ww = wi & 7;
    const int ih = n / 7, iw = n - ih * 7;
    int h = wh * 7 + ih + 3; if (h >= 56) h -= 56;     // roll(-3)
    int w = ww * 7 + iw + 3; if (w >= 56) w -= 56;
    const size_t src = ((size_t)b * 3136 + (size_t)h * 56 + w) * 512;
    const size_t dst = (size_t)row * 512;
    ln_one(xa + src, ga, bea, xw + dst, lane);
    ln_one(xb + src, gb, beb, yw + dst, lane);
}

// ---------------------------------------------------------------------------
// 8-wave GEMM mainloop, 2-PHASE PIPELINED: 128(M)x256(N) tile, BK=32,
// 16 K-steps, double-buffered LDS (2 x 24 KB = 48 KB -> 3 blocks/CU).
// Per iter: issue next half-tile's global_load_lds FIRST, then ds_read+MFMA
// on current buffer, then one vmcnt(0)+barrier (loads overlap compute).
// Swizzle: 4 chunks (16B) per row; physical chunk = logical ^ ((row>>1)&3).
// Within a 16-lane b128 phase: 2 lanes/bank -> conflict-free.
// ---------------------------------------------------------------------------
#define GEMM8P_MAIN()                                                           \
    __shared__ __align__(16) u16 As[2][128 * 32];                               \
    __shared__ __align__(16) u16 Bs[2][256 * 32];                               \
    const int tid = threadIdx.x;                                                \
    const int lane = tid & 63;                                                  \
    const int wv = tid >> 6;                                                    \
    const int wm = wv >> 2, wn = wv & 3;                                        \
    const int rowl = lane & 15, kg = lane >> 4;                                 \
    const int fsw = (rowl >> 1) & 3;          /* frag-read chunk swizzle */     \
    f32x4 acc[4][4];                                                            \
    for (int i = 0; i < 4; ++i)                                                 \
        for (int j = 0; j < 4; ++j)                                             \
            acc[i][j] = (f32x4){0.f, 0.f, 0.f, 0.f};                            \
    const int srow = tid >> 2;                /* 0..127 */                      \
    const int scol = ((tid & 3) ^ ((tid >> 3) & 3)) * 8;  /* pre-swizzled */    \
    const u16* Ab  = Asrc + (size_t)(mt * 128 + srow) * 512 + scol;             \
    const u16* Bb0 = Bsrc + (size_t)srow * 512 + scol;                          \
    const u16* Bb1 = Bsrc + (size_t)(128 + srow) * 512 + scol;                  \
    /* prologue: stage kt=0 into buffer 0 */                                    \
    ASYNC_COPY16(Ab,  (char*)&As[0][0] + tid * 16);                             \
    ASYNC_COPY16(Bb0, (char*)&Bs[0][0] + tid * 16);                             \
    ASYNC_COPY16(Bb1, (char*)&Bs[0][0] + 8192 + tid * 16);                      \
    asm volatile("s_waitcnt vmcnt(0)" ::: "memory");                            \
    __syncthreads();                                                            \
    for (int kt = 0; kt < 16; ++kt) {                                           \
        const int cur = kt & 1, nxt = cur ^ 1;                                  \
        if (kt < 15) {                                                          \
            const int k1 = (kt + 1) * 32;                                       \
            ASYNC_COPY16(Ab + k1,  (char*)&As[0][0] + nxt * 8192 + tid * 16);   \
            ASYNC_COPY16(Bb0 + k1, (char*)&Bs[0][0] + nxt * 16384 + tid * 16);  \
            ASYNC_COPY16(Bb1 + k1, (char*)&Bs[0][0] + nxt * 16384 + 8192 + tid * 16); \
        }                                                                       \
        const u16* Asb = &As[cur][0];                                           \
        const u16* Bsb = &Bs[cur][0];                                           \
        bf16x8 af[4], bfr[4];                                                   \
        _Pragma("unroll")                                                       \
        for (int i = 0; i < 4; ++i)                                             \
            af[i] = *(const bf16x8*)(Asb + (wm * 64 + i * 16 + rowl) * 32       \
                                         + ((kg ^ fsw) * 8));                   \
        _Pragma("unroll")                                                       \
        for (int j = 0; j < 4; ++j)                                             \
            bfr[j] = *(const bf16x8*)(Bsb + (wn * 64 + j * 16 + rowl) * 32      \
                                          + ((kg ^ fsw) * 8));                  \
        _Pragma("unroll")                                                       \
        for (int i = 0; i < 4; ++i) {                                           \
            _Pragma("unroll")                                                   \
            for (int j = 0; j < 4; ++j)                                         \
                acc[i][j] = __builtin_amdgcn_mfma_f32_16x16x32_bf16(            \
                    af[i], bfr[j], acc[i][j], 0, 0, 0);                         \
        }                                                                       \
        asm volatile("s_waitcnt vmcnt(0)" ::: "memory");                        \
        __syncthreads();                                                        \
    }

// Kernel 3: q/k/v projection.  Grid 2352 = 392 mt x 6 nt (nt-fastest,
// bijective XCD swizzle).  nt 0-1: q (A=yw); 2-3: k (A=xw); 4-5: v (A=xw).
__global__ __launch_bounds__(512) void gemm_qkv_kernel(
    const u16* __restrict__ xw, const u16* __restrict__ yw,
    const u16* __restrict__ Wt,
    const float* __restrict__ bqkv_a, const float* __restrict__ bqkv_b,
    u16* __restrict__ qb, u16* __restrict__ kb, u16* __restrict__ vb)
{
    const int bid = blockIdx.x;                       // 2352 = 8 * 294
    const int swz = (bid & 7) * 294 + (bid >> 3);
    const int nt = swz % 6;
    const int mt = swz / 6;
    const u16* Asrc = (nt < 2) ? yw : xw;
    const u16* Bsrc = Wt + (size_t)(nt * 256) * 512;
    GEMM8P_MAIN()

    u16* dst; const float* bvec; bool isq = false;
    if (nt < 2)      { dst = qb; bvec = bqkv_b; isq = true; }
    else if (nt < 4) { dst = kb; bvec = bqkv_a; }
    else             { dst = vb; bvec = bqkv_a; }
#pragma unroll
    for (int j = 0; j < 4; ++j) {
        const int col = nt * 256 + wn * 64 + j * 16 + rowl;   // 0..1535
        const float bias_ = bvec[col];
        const int pcol = col & 511;
#pragma unroll
        for (int i = 0; i < 4; ++i) {
#pragma unroll
            for (int rr = 0; rr < 4; ++rr) {
                const int row = mt * 128 + wm * 64 + i * 16 + kg * 4 + rr;
                float val = acc[i][j][rr] + bias_;
                if (isq) val *= SCALE_;
                dst[(size_t)row * 512 + pcol] = f2bf(val);
            }
        }
    }
}

// Kernel 5: output projection + bias + window_reverse + roll(+3,+3), fp32 out.
// Grid 784 = 392 mt x 2 nt.
__global__ __launch_bounds__(512) void gemm_proj_kernel(
    const u16* __restrict__ attn_out, const u16* __restrict__ WtProj,
    const float* __restrict__ bproj, float* __restrict__ out)
{
    const int bid = blockIdx.x;                       // 784 = 8 * 98
    const int swz = (bid & 7) * 98 + (bid >> 3);
    const int nt = swz & 1;
    const int mt = swz >> 1;
    const u16* Asrc = attn_out;
    const u16* Bsrc = WtProj + (size_t)(nt * 256) * 512;
    GEMM8P_MAIN()

#pragma unroll
    for (int j = 0; j < 4; ++j) {
        const int col = nt * 256 + wn * 64 + j * 16 + rowl;   // 0..511
        const float bias_ = bproj[col];
#pragma unroll
        for (int i = 0; i < 4; ++i) {
#pragma unroll
            for (int rr = 0; rr < 4; ++rr) {
                const int row = mt * 128 + wm * 64 + i * 16 + kg * 4 + rr;
                const int win = row / 49;
                const int nw = row - win * 49;
                const int b = win >> 6, wi = win & 63;
                const int wh = wi >> 3, ww = wi & 7;
                const int ih = nw / 7, iw = nw - ih * 7;
                int h = wh * 7 + ih + 3; if (h >= 56) h -= 56;  // roll(+3)
                int w = ww * 7 + iw + 3; if (w >= 56) w -= 56;
                out[((size_t)b * 3136 + (size_t)h * 56 + w) * 512 + col] =
                    acc[i][j][rr] + bias_;
            }
        }
    }
}

// ---------------------------------------------------------------------------
// Kernel 4: MFMA windowed cross-attention.  One block per (window, head),
// 4 waves; wave w owns S row-tile w (16 rows).  biasT is col-major ->
// f32x4 bias loads.
// ---------------------------------------------------------------------------
__global__ __launch_bounds__(256) void attn_kernel(
    const u16* __restrict__ qb, const u16* __restrict__ kb,
    const u16* __restrict__ vb, const float* __restrict__ biasT,
    u16* __restrict__ attn_out)
{
    __shared__ __align__(16) u16 VT[32 * 64];   // [d][chunk^(d&7)*8 + j&7]
    __shared__ __align__(16) u16 P[64 * 64];    // [row][chunk^(row&7)*8 + j&7]
    const int tid = threadIdx.x;
    const int wh_id = blockIdx.x;               // win*16 + head
    const int win = wh_id >> 4, head = wh_id & 15;
    const int lane = tid & 63, wvi = tid >> 6;
    const int rowl = lane & 15, kg = lane >> 4;
    const size_t base = (size_t)win * 49 * 512 + head * 32;

    // ---- stage V^T
    {
        const int j = tid >> 2, d0 = (tid & 3) * 8;
        const bf16x8 v8 = *(const bf16x8*)(vb + base + (size_t)j * 512 + d0);
        const int cj = j >> 3, je = j & 7;
#pragma unroll
        for (int m = 0; m < 8; ++m) {
            const int d = d0 + m;
            VT[d * 64 + ((cj ^ (d & 7)) * 8) + je] = (u16)v8[m];
        }
    }

    // ---- S = Q K^T (direct-global fragments)
    const bf16x8 aq = *(const bf16x8*)(qb + base + (size_t)(wvi * 16 + rowl) * 512 + kg * 8);
    f32x4 accS[4];
#pragma unroll
    for (int j = 0; j < 4; ++j) {
        const bf16x8 bk = *(const bf16x8*)(kb + base + (size_t)(j * 16 + rowl) * 512 + kg * 8);
        accS[j] = __builtin_amdgcn_mfma_f32_16x16x32_bf16(
            aq, bk, (f32x4){0.f, 0.f, 0.f, 0.f}, 0, 0, 0);
    }

    // ---- + bias (rpb + window mask + pad mask), f32x4 per j
    const int wi = win & 63;
    const int mid = (((wi >> 3) == 7) ? 2 : 0) + (((wi & 7) == 7) ? 1 : 0);
    const float* bptr = biasT + ((size_t)(mid * 16 + head) << 12);
#pragma unroll
    for (int j = 0; j < 4; ++j) {
        const f32x4 bv4 = *(const f32x4*)(bptr + (j * 16 + rowl) * 64 + wvi * 16 + kg * 4);
#pragma unroll
        for (int r = 0; r < 4; ++r)
            accS[j][r] += bv4[r];
    }

    // ---- softmax rows (row lives in one 16-lane group)
    float rinv[4];
#pragma unroll
    for (int r = 0; r < 4; ++r) {
        float m = fmaxf(fmaxf(accS[0][r], accS[1][r]), fmaxf(accS[2][r], accS[3][r]));
#pragma unroll
        for (int o = 1; o <= 8; o <<= 1) m = fmaxf(m, __shfl_xor(m, o));
        float s = 0.f;
#pragma unroll
        for (int j = 0; j < 4; ++j) {
            accS[j][r] = __expf(accS[j][r] - m);
            s += accS[j][r];
        }
#pragma unroll
        for (int o = 1; o <= 8; o <<= 1) s += __shfl_xor(s, o);
        rinv[r] = __frcp_rn(s);
    }

    // ---- P -> LDS (bf16, unnormalized; wave-local rows)
#pragma unroll
    for (int j = 0; j < 4; ++j) {
        const int c = j * 2 + (rowl >> 3);
#pragma unroll
        for (int r = 0; r < 4; ++r) {
            const int row = wvi * 16 + kg * 4 + r;
            P[row * 64 + ((c ^ (row & 7)) * 8) + (rowl & 7)] = f2bf(accS[j][r]);
        }
    }

    __syncthreads();

    // ---- O = P V
    f32x4 accO[2];
#pragma unroll
    for (int dt = 0; dt < 2; ++dt) {
        accO[dt] = (f32x4){0.f, 0.f, 0.f, 0.f};
#pragma unroll
        for (int kb_ = 0; kb_ < 2; ++kb_) {
            const int prow = wvi * 16 + rowl;
            const int ca = kb_ * 4 + kg;
            const bf16x8 ap = *(const bf16x8*)(P + prow * 64 + ((ca ^ (prow & 7)) * 8));
            const int vd = dt * 16 + rowl;
            const bf16x8 bv = *(const bf16x8*)(VT + vd * 64 + ((ca ^ (vd & 7)) * 8));
            accO[dt] = __builtin_amdgcn_mfma_f32_16x16x32_bf16(ap, bv, accO[dt], 0, 0, 0);
        }
    }

    // ---- scale by 1/sum, store rows < 49
#pragma unroll
    for (int dt = 0; dt < 2; ++dt) {
#pragma unroll
        for (int r = 0; r < 4; ++r) {
            const int i = wvi * 16 + kg * 4 + r;
            if (i < 49)
                attn_out[base + (size_t)i * 512 + dt * 16 + rowl] =
                    f2bf(accO[dt][r] * rinv[r]);
        }
    }
}

// ---------------------------------------------------------------------------
extern "C" void kernel_launch(void* const* d_in, const int* in_sizes, int n_in,
                              void* d_out, int out_size, void* d_ws, size_t ws_size,
                              hipStream_t stream) {
    (void)in_sizes; (void)n_in; (void)out_size; (void)ws_size;
    const float* rescaled = (const float*)d_in[0];
    const float* rescaler = (const float*)d_in[1];
    const float* gamma_a  = (const float*)d_in[2];
    const float* beta_a   = (const float*)d_in[3];
    const float* gamma_b  = (const float*)d_in[4];
    const float* beta_b   = (const float*)d_in[5];
    const float* Wqkv_a   = (const float*)d_in[6];
    const float* bqkv_a   = (const float*)d_in[7];
    const float* Wqkv_b   = (const float*)d_in[8];
    const float* bqkv_b   = (const float*)d_in[9];
    const float* rpb      = (const float*)d_in[10];
    const float* Wproj    = (const float*)d_in[11];
    const float* bproj    = (const float*)d_in[12];
    float* out = (float*)d_out;

    char* ws = (char*)d_ws;
    const size_t SZ = (size_t)MTOT * 512 * 2;     // 51,380,224 B per bf16 plane
    u16* xw = (u16*)ws;                           // reused as attn_out
    u16* yw = (u16*)(ws + SZ);
    u16* qb = (u16*)(ws + 2 * SZ);
    u16* kb = (u16*)(ws + 3 * SZ);
    u16* vb = (u16*)(ws + 4 * SZ);
    u16* Wt = (u16*)(ws + 5 * SZ);                // 2 MB
    float* biasT = (float*)(ws + 5 * SZ + 2097152);// 1 MB
    u16* attn_out = xw;

    wconv_kernel<<<4096, 256, 0, stream>>>(Wqkv_a, Wqkv_b, Wproj, Wt);
    build_bias_kernel<<<64, 256, 0, stream>>>(rpb, biasT);
    ln_window_kernel<<<MTOT / 4, 256, 0, stream>>>(
        rescaled, rescaler, gamma_a, beta_a, gamma_b, beta_b, xw, yw);
    gemm_qkv_kernel<<<2352, 512, 0, stream>>>(
        xw, yw, Wt, bqkv_a, bqkv_b, qb, kb, vb);
    attn_kernel<<<16384, 256, 0, stream>>>(qb, kb, vb, biasT, attn_out);
    gemm_proj_kernel<<<784, 512, 0, stream>>>(
        attn_out, Wt + (size_t)1536 * 512, bproj, out);
}